// Round 17
// baseline (228.157 us; speedup 1.0000x reference)
//
#include <hip/hip_runtime.h>

// SiamFC cross-correlation: out[n,0,oh,ow] = sum_{c,i,j} x[n,c,oh+i,ow+j] * z[n,c,i,j]
// n=256, c=256, z=6x6, x=26x26, out=21x21.
//
// Round-17: 16 independent single-wave pipelines per CU, ZERO barriers.
// Block = 64 threads (1 wave), CCON=1, TRIPLE-buffered LDS (8.1 KB -> 8 KB
// granule -> 16 blocks/CU at launch_bounds(64,4); grid 4096 = exactly 16/CU).
// Depth-2 DMA: x(r+1), x(r+2) in flight; per-round s_waitcnt vmcnt(3) drains
// x(r) + z(r) (z register ping-pong zqA/zqB, loaded into the VMEM queue so the
// counted vmcnt covers it). Same-wave gload_lds consumption -> no s_barrier.
// Lane map: q=bits0-1 (col quarter {0-5,6-10,11-15,16-20}), t=bits2-4 (3-row
// tile, 7 used), h=bit5 (z rows 3h..3h+2). Uniform 6 ds_read_b64/row, 324
// FMA/(m-row) group; dead col/loads masked at store. Epilogue: shfl_xor(32)
// h-fold + direct ws stores (no LDS reuse, no atomics); K2 folds 16 splits.

#define OH 21
#define OW 21
#define CBUF 676               // floats per channel buffer
#define NTHREADS 64
#define NSPLITS 16
#define WS_STRIDE 448          // per-(split,n) ws slot (floats)

typedef __attribute__((address_space(3))) unsigned int lds_u32_t;
typedef __attribute__((address_space(1))) const unsigned int glb_u32_t;

__device__ __forceinline__ void gload16(const void* g, void* l) {
    __builtin_amdgcn_global_load_lds((glb_u32_t*)g, (lds_u32_t*)l, 16, 0, 0);
}

__global__ __launch_bounds__(NTHREADS, 4)
void siamfc_xcorr_part(const float* __restrict__ z, const float* __restrict__ x,
                       float* __restrict__ ws) {
    __shared__ __align__(16) float lds[3 * CBUF + 4];   // 8128 B (+4 guard: dead q3 row-25 reads)

    const int tid = threadIdx.x;        // == lane
    const int bid = blockIdx.x;
    const int n     = bid >> 4;
    const int split = bid & 15;
    const int cb0   = split * 16;       // 16 channels per block, 16 rounds

    const int q = tid & 3;              // col quarter
    const int t = (tid >> 2) & 7;       // 3-row tile, t==7 idle in compute
    const int h = tid >> 5;             // z rows 3h..3h+2
    const bool active = (t < 7);
    const int uq = (q == 0) ? 0 : (q == 1) ? 3 : (q == 2) ? 5 : 8;  // float2 start unit
    const int dq = (q == 2) ? 1 : 0;                                // xr base offset
    const int sq = (q == 0) ? 0 : (q == 1) ? 6 : (q == 2) ? 11 : 16; // first col
    const int wq = (q == 0) ? 6 : 5;                                // valid cols

    const float4* xg4 = (const float4*)x + (size_t)n * (256 * 169);
    const float2* zg2 = (const float2*)z + (size_t)n * (256 * 18);

    // 3 gload_lds per round: channel = cb0 + r (169 quads: 64 + 64 + 41)
    auto issue = [&](int r, int b) {
        const float4* xsrc = xg4 + (size_t)(cb0 + r) * 169;
        float* xb = lds + b * CBUF;
        gload16(xsrc + tid,       xb);
        gload16(xsrc + 64 + tid,  xb + 64 * 4);
        if (tid < 41)
            gload16(xsrc + 128 + tid, xb + 128 * 4);
    };
    // 9 float2 z loads -> registers (enter the VMEM queue; drained by vmcnt)
    auto zload = [&](int r, float2 (&zq)[9]) {
        const float2* zp = zg2 + (size_t)(cb0 + r) * 18 + 9 * h;
        #pragma unroll
        for (int e = 0; e < 9; ++e) zq[e] = zp[e];
    };

    float acc[18];
    #pragma unroll
    for (int v = 0; v < 18; ++v) acc[v] = 0.f;

    int bA = 0, bB = 1, bC = 2;         // consume bA; bB = next; bC = issue target
    float2 zqA[9], zqB[9];

    // prologue: queue = [x(0):3][z(0):9][x(1):3]  (steady-state invariant)
    issue(0, bA);
    zload(0, zqA);
    issue(1, bB);

    auto round = [&](int r, float2 (&zuse)[9], float2 (&zpre)[9]) {
        if (r < 15) { asm volatile("s_waitcnt vmcnt(3)" ::: "memory"); }  // x(r)+z(r) done, x(r+1) flying
        else        { asm volatile("s_waitcnt vmcnt(0)" ::: "memory"); }
        if (r + 1 < 16) zload(r + 1, zpre);      // in flight under compute(r)
        if (active) {
            float zv[3][6];
            #pragma unroll
            for (int e = 0; e < 9; ++e) {
                zv[e / 3][2 * (e % 3)]     = zuse[e].x;
                zv[e / 3][2 * (e % 3) + 1] = zuse[e].y;
            }
            const float2* xcb = (const float2*)(lds + bA * CBUF);
            #pragma unroll
            for (int m = 0; m < 5; ++m) {        // x rows 3t+3h+m (<=25)
                const int row = 3 * t + 3 * h + m;
                const float2* rp = xcb + row * 13 + uq;
                float xr[12];                    // floats 2uq .. 2uq+11
                #pragma unroll
                for (int s = 0; s < 6; ++s) {
                    float2 e = rp[s];
                    xr[2 * s] = e.x; xr[2 * s + 1] = e.y;
                }
                #pragma unroll
                for (int zr = 0; zr < 3; ++zr) {
                    const int a = m - zr;        // output row 3t+a
                    if (a >= 0 && a < 3) {
                        #pragma unroll
                        for (int j = 0; j < 6; ++j)
                            #pragma unroll
                            for (int o = 0; o < 6; ++o)   // col sq+o (o=5 dead for q>0)
                                acc[a * 6 + o] = fmaf(zv[zr][j], xr[dq + o + j], acc[a * 6 + o]);
                    }
                }
            }
        }
        if (r + 2 < 16) issue(r + 2, bC);        // depth-2 prefetch
        int tmp = bA; bA = bB; bB = bC; bC = tmp;
    };

    #pragma unroll 1
    for (int r = 0; r < 16; r += 2) {            // 16 rounds, even -> clean ping-pong
        round(r,     zqA, zqB);
        round(r + 1, zqB, zqA);
    }

    // ---- fold h (lane bit 5) in-wave; h=0 lanes hold full (q,t) partials
    #pragma unroll
    for (int v = 0; v < 18; ++v) acc[v] += __shfl_xor(acc[v], 32, 64);

    // ---- direct store of this split's 441 partials (no LDS, no atomics)
    if (active && h == 0) {
        float* wp = ws + (size_t)(split * 256 + n) * WS_STRIDE;
        #pragma unroll
        for (int a = 0; a < 3; ++a) {
            const int row = 3 * t + a;
            for (int o = 0; o < wq; ++o)
                wp[row * OW + sq + o] = acc[a * 6 + o];
        }
    }
}

__global__ __launch_bounds__(WS_STRIDE, 4)
void siamfc_reduce(const float* __restrict__ ws, float* __restrict__ out) {
    const int n = blockIdx.x;
    const int o = threadIdx.x;
    if (o >= OH * OW) return;
    float s = 0.f;
    #pragma unroll
    for (int sp = 0; sp < NSPLITS; ++sp)
        s += ws[(size_t)(sp * 256 + n) * WS_STRIDE + o];
    out[(size_t)n * (OH * OW) + o] = s;
}

extern "C" void kernel_launch(void* const* d_in, const int* in_sizes, int n_in,
                              void* d_out, int out_size, void* d_ws, size_t ws_size,
                              hipStream_t stream) {
    const float* z = (const float*)d_in[0];
    const float* x = (const float*)d_in[1];
    float* out = (float*)d_out;
    float* wsp = (float*)d_ws;
    siamfc_xcorr_part<<<dim3(256 * NSPLITS), dim3(NTHREADS), 0, stream>>>(z, x, wsp);
    siamfc_reduce<<<dim3(256), dim3(WS_STRIDE), 0, stream>>>(wsp, out);
}